// Round 5
// baseline (1050.029 us; speedup 1.0000x reference)
//
#include <hip/hip_runtime.h>
#include <math.h>

#define TPB   256
#define NPB   256      // nodes per bucket (shift 8)
#define MAXNB 512      // supports N <= 131072
#define BCAP  10240    // staging capacity per bucket (expected 8192, sigma~90 -> no overflow)
#define ITEMS 16       // edges per thread in phase-1 tile (625 blocks -> 2.4/CU)
#define CPAD  16       // pad bucket counters to one per 64B line

static inline int gridFor(size_t n) { return (int)((n + TPB - 1) / TPB); }

// ================= node linear transforms =================

__global__ void __launch_bounds__(TPB) k_lin1(
    const float* __restrict__ x,
    const float* __restrict__ Wl, const float* __restrict__ bl,
    const float* __restrict__ Wr, const float* __restrict__ br,
    float* __restrict__ xl, float* __restrict__ xr, int N)
{
  int idx = blockIdx.x * TPB + threadIdx.x;
  if (idx >= N * 18) return;
  int i = idx / 18, t = idx % 18;
  bool left = t < 9;
  int j = left ? t : t - 9;
  const float4* W4 = (const float4*)((left ? Wl : Wr) + j * 64);
  float s = (left ? bl : br)[j];
  const float4* xi4 = (const float4*)(x + (size_t)i * 64);
#pragma unroll
  for (int f = 0; f < 16; f++) {
    float4 xv = xi4[f], wv = W4[f];
    s = fmaf(xv.x, wv.x, s);
    s = fmaf(xv.y, wv.y, s);
    s = fmaf(xv.z, wv.z, s);
    s = fmaf(xv.w, wv.w, s);
  }
  (left ? xl : xr)[(size_t)i * 9 + j] = s;
}

__global__ void __launch_bounds__(TPB) k_lin2(
    const float* __restrict__ h1, const float* __restrict__ bias1,
    const float* __restrict__ Wl, const float* __restrict__ bl,
    const float* __restrict__ Wr, const float* __restrict__ br,
    float* __restrict__ xl, float* __restrict__ xr, int N)
{
  int idx = blockIdx.x * TPB + threadIdx.x;
  if (idx >= N * 40) return;
  int i = idx / 40, t = idx % 40;
  float hr[9];
#pragma unroll
  for (int k = 0; k < 9; k++) hr[k] = fmaxf(h1[(size_t)i * 9 + k] + bias1[k], 0.0f);
  bool left = t < 20;
  int j = left ? t : t - 20;
  const float* W = (left ? Wl : Wr) + j * 9;
  float s = (left ? bl : br)[j];
#pragma unroll
  for (int k = 0; k < 9; k++) s = fmaf(hr[k], W[k], s);
  (left ? xl : xr)[(size_t)i * 20 + j] = s;
}

// ============== phase 1: bin edges by dst-bucket (LDS multisplit) ==========
// record: x = eid | (dst_local << 22), y = src.  (E < 2^22, dst_local < 256)

__global__ void __launch_bounds__(TPB) k_bin(
    const int* __restrict__ ei, int* __restrict__ bucketCntP,
    int2* __restrict__ staging, int E, int NB)
{
  __shared__ int hist[MAXNB];
  __shared__ int base[MAXNB];
  int tid = threadIdx.x;
  size_t tile0 = (size_t)blockIdx.x * (TPB * ITEMS);
  for (int i = tid; i < NB; i += TPB) hist[i] = 0;
  __syncthreads();
  for (int it = 0; it < ITEMS; ++it) {
    size_t e = tile0 + (size_t)it * TPB + tid;
    if (e < (size_t)E) {
      int dst = ei[(size_t)E + e];
      atomicAdd(&hist[dst >> 8], 1);
    }
  }
  __syncthreads();
  for (int i = tid; i < NB; i += TPB) {
    int c = hist[i];
    base[i] = c ? atomicAdd(&bucketCntP[(size_t)i * CPAD], c) : 0;
    hist[i] = 0;
  }
  __syncthreads();
  for (int it = 0; it < ITEMS; ++it) {
    size_t e = tile0 + (size_t)it * TPB + tid;
    if (e < (size_t)E) {
      int src = ei[e];
      int dst = ei[(size_t)E + e];
      int b = dst >> 8;
      int r = atomicAdd(&hist[b], 1);
      staging[(size_t)b * BCAP + base[b] + r] =
          make_int2((int)e | ((dst & 255) << 22), src);
    }
  }
}

// ============== scan bucket counts -> bucket edge bases ==============

__global__ void __launch_bounds__(MAXNB) k_scanb(
    const int* __restrict__ bucketCntP, int* __restrict__ bucketBase, int NB)
{
  __shared__ int s[MAXNB];
  int tid = threadIdx.x;
  int v = (tid < NB) ? bucketCntP[(size_t)tid * CPAD] : 0;
  s[tid] = v;
  __syncthreads();
  for (int off = 1; off < MAXNB; off <<= 1) {
    int u = (tid >= off) ? s[tid - off] : 0;
    __syncthreads();
    s[tid] += u;
    __syncthreads();
  }
  if (tid < NB) bucketBase[tid] = s[tid] - v;   // exclusive
}

// ============== phase 2: per-bucket tight CSR (L2-local writes) ============

__global__ void __launch_bounds__(TPB) k_csr(
    const int2* __restrict__ staging, const int* __restrict__ bucketCntP,
    const int* __restrict__ bucketBase,
    int* __restrict__ rowptr, int* __restrict__ degO,
    int* __restrict__ src_csr, int* __restrict__ eid_csr, int N)
{
  int b = blockIdx.x, tid = threadIdx.x;
  int n0 = b << 8;
  int recCnt = bucketCntP[(size_t)b * CPAD];
  int ebase = bucketBase[b];
  const int2* rec = staging + (size_t)b * BCAP;
  __shared__ int deg_s[NPB];
  __shared__ int pfx[NPB];
  __shared__ int cur[NPB];
  deg_s[tid] = 0;
  __syncthreads();
  for (int r = tid; r < recCnt; r += TPB)
    atomicAdd(&deg_s[(rec[r].x >> 22) & 255], 1);
  __syncthreads();
  pfx[tid] = deg_s[tid];
  __syncthreads();
  for (int off = 1; off < NPB; off <<= 1) {
    int u = (tid >= off) ? pfx[tid - off] : 0;
    __syncthreads();
    pfx[tid] += u;
    __syncthreads();
  }
  int excl = pfx[tid] - deg_s[tid];
  int n = n0 + tid;
  if (n < N) { rowptr[n] = ebase + excl; degO[n] = deg_s[tid]; }
  cur[tid] = ebase + excl;
  __syncthreads();
  for (int r = tid; r < recCnt; r += TPB) {
    int2 rc = rec[r];
    int dl = (rc.x >> 22) & 255;
    int eid = rc.x & 0x3FFFFF;
    int pos = atomicAdd(&cur[dl], 1);
    src_csr[pos] = rc.y;
    eid_csr[pos] = eid;
  }
}

// ======= gather + project edge attrs for BOTH layers, CSR slot order =======
// ONE-SHOT grid (no grid-stride loop): 16 lanes per slot, every slot's line
// request is issued by an independent thread group -> MLP bounded only by
// occupancy (the round-3 grid-stride version serialized on its dependent
// chain at 1.35 TB/s).  Lane j computes flat channels j and j+16 of the 29
// projection channels (9 layer-1 + 20 layer-2); f-order 0..15 matches the
// original in-attn accumulation exactly.
//   flat k: k<9 -> p1 row k ; 9<=k<29 -> p2 row k-9.

__global__ void __launch_bounds__(TPB) k_rproj(
    const int* __restrict__ eid_csr, const float4* __restrict__ eattr4,
    const float* __restrict__ We1, const float* __restrict__ We2,
    float* __restrict__ p1, float* __restrict__ p2, int E)
{
  int idx = blockIdx.x * TPB + threadIdx.x;
  int slot = idx >> 4;
  int j = idx & 15;
  if (slot >= E) return;

  // two weight rows per lane (k0 = j, k1 = j+16; k1 valid while j < 13)
  const float4* q0 = (const float4*)((j < 9) ? (We1 + j * 16) : (We2 + (j - 9) * 16));
  const float4* q1 = (const float4*)((j < 13) ? (We2 + (j + 7) * 16) : We2);
  float w0[16], w1[16];
  {
    float4 v0 = q0[0], v1 = q0[1], v2 = q0[2], v3 = q0[3];
    w0[0]=v0.x; w0[1]=v0.y; w0[2]=v0.z; w0[3]=v0.w;
    w0[4]=v1.x; w0[5]=v1.y; w0[6]=v1.z; w0[7]=v1.w;
    w0[8]=v2.x; w0[9]=v2.y; w0[10]=v2.z; w0[11]=v2.w;
    w0[12]=v3.x; w0[13]=v3.y; w0[14]=v3.z; w0[15]=v3.w;
  }
  {
    float4 v0 = q1[0], v1 = q1[1], v2 = q1[2], v3 = q1[3];
    w1[0]=v0.x; w1[1]=v0.y; w1[2]=v0.z; w1[3]=v0.w;
    w1[4]=v1.x; w1[5]=v1.y; w1[6]=v1.z; w1[7]=v1.w;
    w1[8]=v2.x; w1[9]=v2.y; w1[10]=v2.z; w1[11]=v2.w;
    w1[12]=v3.x; w1[13]=v3.y; w1[14]=v3.z; w1[15]=v3.w;
  }

  int eid = eid_csr[slot];                    // 16 lanes same addr -> merged
  const float4* a4 = eattr4 + (size_t)eid * 4;
  float4 A0 = a4[0], A1 = a4[1], A2 = a4[2], A3 = a4[3];  // one 64B line
  float a[16];
  a[0]=A0.x; a[1]=A0.y; a[2]=A0.z; a[3]=A0.w;
  a[4]=A1.x; a[5]=A1.y; a[6]=A1.z; a[7]=A1.w;
  a[8]=A2.x; a[9]=A2.y; a[10]=A2.z; a[11]=A2.w;
  a[12]=A3.x; a[13]=A3.y; a[14]=A3.z; a[15]=A3.w;
  float s0 = 0.0f, s1 = 0.0f;
#pragma unroll
  for (int f = 0; f < 16; f++) {
    s0 = fmaf(a[f], w0[f], s0);
    s1 = fmaf(a[f], w1[f], s1);
  }
  if (j < 9) p1[(size_t)slot * 9 + j] = s0;
  else       p2[(size_t)slot * 20 + (j - 9)] = s0;
  if (j < 13) p2[(size_t)slot * 20 + (7 + j)] = s1;
}

// ========== fused GATv2 attention: online softmax, virtual self-loop =======
// L lanes cooperate on one (node, head) row; each lane keeps a partial
// online-softmax state over edges p = lane, lane+L, ...; states merged via
// a shfl_xor butterfly at the end.
// PROJ: ea = precomputed projections [E][H*C] in CSR slot order (no We).
// !PROJ (fallback when ws too small): ea = raw eattr, gather via eid_csr,
// project in-kernel with We in registers.

template <int H, int C, int L, bool PROJ>
__global__ void __launch_bounds__(TPB) k_attn(
    const int* __restrict__ rowptr, const int* __restrict__ deg,
    const int* __restrict__ src_csr, const int* __restrict__ eid_csr,
    const float* __restrict__ ea,     // proj buffer if PROJ, else raw eattr
    const float* __restrict__ xl, const float* __restrict__ xr,
    const float* __restrict__ We, const float* __restrict__ att,
    const float* __restrict__ bias,  // nullptr -> raw output
    float* __restrict__ out, int N)
{
  constexpr int HC = H * C;
  int idx = blockIdx.x * TPB + threadIdx.x;
  if (idx >= N * H * L) return;
  int l = idx & (L - 1);          // lane within group (L divides 64)
  int g = idx / L;                // (node, head) group
  int n = g / H, h = g - n * H;

  float w[PROJ ? 1 : C][PROJ ? 1 : 16];
  if constexpr (!PROJ) {
#pragma unroll
    for (int c = 0; c < C; c++)
#pragma unroll
      for (int f = 0; f < 16; f++) w[c][f] = We[(h * C + c) * 16 + f];
  }
  float attv[C], xrv[C];
#pragma unroll
  for (int c = 0; c < C; c++) {
    attv[c] = att[h * C + c];
    xrv[c] = xr[(size_t)n * HC + h * C + c];
  }

  int r0 = rowptr[n];
  int dg = deg[n];

  // finite sentinel (not -inf) so empty-lane merges give exp(0)=1 on a zero
  // accumulator instead of exp(-inf+inf)=NaN.
  float mx = -3.0e38f, den = 0.0f;
  float acc[C], ea_sum[C];
#pragma unroll
  for (int c = 0; c < C; c++) { acc[c] = 0.0f; ea_sum[c] = 0.0f; }

  for (int p = l; p < dg; p += L) {
    int pos = r0 + p;
    float eav[C];
    if constexpr (PROJ) {
      const float* pp = ea + (size_t)pos * HC + h * C;
#pragma unroll
      for (int c = 0; c < C; c++) eav[c] = pp[c];
    } else {
      float a[16];
      const float4* a4 = (const float4*)(ea + (size_t)eid_csr[pos] * 16);
#pragma unroll
      for (int k = 0; k < 4; k++) {
        float4 v = a4[k];
        a[4 * k + 0] = v.x; a[4 * k + 1] = v.y; a[4 * k + 2] = v.z; a[4 * k + 3] = v.w;
      }
#pragma unroll
      for (int c = 0; c < C; c++) {
        float s = 0.0f;
#pragma unroll
        for (int f = 0; f < 16; f++) s = fmaf(a[f], w[c][f], s);
        eav[c] = s;
      }
    }
    int srcn = src_csr[pos];
    const float* xs = xl + (size_t)srcn * HC + h * C;
    float xv[C];
#pragma unroll
    for (int c = 0; c < C; c++) xv[c] = xs[c];
    float lg = 0.0f;
#pragma unroll
    for (int c = 0; c < C; c++) {
      ea_sum[c] += eav[c];
      float m = xv[c] + xrv[c] + eav[c];
      m = (m >= 0.0f) ? m : 0.2f * m;
      lg = fmaf(m, attv[c], lg);
    }
    float nm = fmaxf(mx, lg);
    float s = expf(mx - nm);     // 0 when mx is sentinel and lg real
    float wE = expf(lg - nm);
    den = den * s + wE;
#pragma unroll
    for (int c = 0; c < C; c++) acc[c] = fmaf(acc[c], s, wE * xv[c]);
    mx = nm;
  }

  // ---- merge the L partial online-softmax states (xor butterfly) ----
#pragma unroll
  for (int off = 1; off < L; off <<= 1) {
    float omx  = __shfl_xor(mx, off, 64);
    float oden = __shfl_xor(den, off, 64);
    float nm = fmaxf(mx, omx);
    float s1 = expf(mx - nm);    // both sentinel -> exp(0)=1, scales zeros
    float s2 = expf(omx - nm);
    den = den * s1 + oden * s2;
#pragma unroll
    for (int c = 0; c < C; c++) {
      float oa = __shfl_xor(acc[c], off, 64);
      float oe = __shfl_xor(ea_sum[c], off, 64);
      acc[c] = acc[c] * s1 + oa * s2;
      ea_sum[c] += oe;
    }
    mx = nm;
  }

  // virtual self-loop: src = n, attr projection = mean of edge projections
  // (computed redundantly on all L lanes -- identical merged state)
  {
    float invd = 1.0f / fmaxf((float)dg, 1.0f);
    const float* xs = xl + (size_t)n * HC + h * C;
    float xv[C];
#pragma unroll
    for (int c = 0; c < C; c++) xv[c] = xs[c];
    float lg = 0.0f;
#pragma unroll
    for (int c = 0; c < C; c++) {
      float m = xv[c] + xrv[c] + ea_sum[c] * invd;
      m = (m >= 0.0f) ? m : 0.2f * m;
      lg = fmaf(m, attv[c], lg);
    }
    float nm = fmaxf(mx, lg);
    float s = expf(mx - nm);
    float wE = expf(lg - nm);
    den = den * s + wE;
#pragma unroll
    for (int c = 0; c < C; c++) acc[c] = fmaf(acc[c], s, wE * xv[c]);
  }

  float inv = 1.0f / den;
  float* od = out + (size_t)n * HC + h * C;
  // lane-partitioned channel writes
  for (int c = l; c < C; c += L) {
    float v = acc[c] * inv;
    if (bias) v = fmaxf(v + bias[h * C + c], 0.0f);
    od[c] = v;
  }
}

// ================= FC head =================

__global__ void __launch_bounds__(TPB) k_fc1(
    const float* __restrict__ h2, const float* __restrict__ W,
    float* __restrict__ h3, int NN, int Kc)
{
  int o = blockIdx.x;
  int ks = blockIdx.y;
  int k0 = ks * Kc;
  int k1 = min(NN, k0 + Kc);
  float acc[16];
#pragma unroll
  for (int b = 0; b < 16; b++) acc[b] = 0.0f;
  const float* wo = W + (size_t)o * NN;
  for (int k = k0 + threadIdx.x; k < k1; k += TPB) {
    float w = wo[k];
#pragma unroll
    for (int b = 0; b < 16; b++) acc[b] = fmaf(h2[(size_t)b * NN + k], w, acc[b]);
  }
#pragma unroll
  for (int b = 0; b < 16; b++) {
    float v = acc[b];
#pragma unroll
    for (int off = 32; off > 0; off >>= 1) v += __shfl_down(v, off, 64);
    if ((threadIdx.x & 63) == 0) atomicAdd(&h3[b * 100 + o], v);
  }
}

__global__ void __launch_bounds__(TPB) k_fc23(
    const float* __restrict__ h3, const float* __restrict__ fcb1,
    const float* __restrict__ W2, const float* __restrict__ b2,
    const float* __restrict__ W3, const float* __restrict__ b3,
    float* __restrict__ out, int B)
{
  __shared__ float s3[32 * 100];
  __shared__ float s4[32 * 10];
  int tid = threadIdx.x;
  for (int t = tid; t < B * 100; t += TPB)
    s3[t] = fmaxf(h3[t] + fcb1[t % 100], 0.0f);
  __syncthreads();
  if (tid < B * 10) {
    int b = tid / 10, o = tid % 10;
    float s = b2[o];
#pragma unroll
    for (int k = 0; k < 100; k++) s = fmaf(s3[b * 100 + k], W2[o * 100 + k], s);
    s4[tid] = fmaxf(s, 0.0f);
  }
  __syncthreads();
  if (tid < B) {
    float s = b3[0];
#pragma unroll
    for (int k = 0; k < 10; k++) s = fmaf(s4[tid * 10 + k], W3[k], s);
    out[tid] = s;
  }
}

// ================= launch =================

extern "C" void kernel_launch(void* const* d_in, const int* in_sizes, int n_in,
                              void* d_out, int out_size, void* d_ws, size_t ws_size,
                              hipStream_t stream) {
  const float* x      = (const float*)d_in[0];
  const int*   ei     = (const int*)d_in[1];
  const float* eattr  = (const float*)d_in[2];
  const float* W1l = (const float*)d_in[4];  const float* b1l = (const float*)d_in[5];
  const float* W1r = (const float*)d_in[6];  const float* b1r = (const float*)d_in[7];
  const float* We1 = (const float*)d_in[8];  const float* att1 = (const float*)d_in[9];
  const float* bias1 = (const float*)d_in[10];
  const float* W2l = (const float*)d_in[11]; const float* b2l = (const float*)d_in[12];
  const float* W2r = (const float*)d_in[13]; const float* b2r = (const float*)d_in[14];
  const float* We2 = (const float*)d_in[15]; const float* att2 = (const float*)d_in[16];
  const float* bias2 = (const float*)d_in[17];
  const float* fcW1 = (const float*)d_in[18]; const float* fcb1 = (const float*)d_in[19];
  const float* fcW2 = (const float*)d_in[20]; const float* fcb2 = (const float*)d_in[21];
  const float* fcW3 = (const float*)d_in[22]; const float* fcb3 = (const float*)d_in[23];
  float* out = (float*)d_out;

  const int N = in_sizes[0] / 64;                   // 80000
  const int E = in_sizes[2] / 16;                   // 2560000
  const int num_nodes = in_sizes[18] / (100 * 20);  // 5000
  const int B = N / num_nodes;                      // 16
  const int NB = (N + NPB - 1) / NPB;               // 313

  // ---- workspace layout (64B aligned chunks) ----
  char* base = (char*)d_ws;
  size_t off = 0;
  auto alloc = [&](size_t bytes) {
    size_t o = off; off += (bytes + 63) & ~(size_t)63; return o;
  };
  // zero-init region: padded bucket counters + h3
  size_t o_bcnt   = alloc((size_t)NB * CPAD * 4);
  size_t o_h3     = alloc((size_t)B * 100 * 4);
  size_t zeroBytes = off;
  size_t o_bbase  = alloc((size_t)NB * 4);
  size_t o_stage  = alloc((size_t)NB * BCAP * 8);
  size_t o_rowptr = alloc((size_t)N * 4);
  size_t o_deg    = alloc((size_t)N * 4);
  size_t o_srcc   = alloc((size_t)E * 4);
  size_t o_eidc   = alloc((size_t)E * 4);
  size_t o_xl1    = alloc((size_t)N * 9 * 4);
  size_t o_xr1    = alloc((size_t)N * 9 * 4);
  size_t o_xl2    = alloc((size_t)N * 20 * 4);
  size_t o_xr2    = alloc((size_t)N * 20 * 4);
  size_t o_h1     = alloc((size_t)N * 9 * 4);
  size_t o_h2     = alloc((size_t)N * 20 * 4);
  size_t o_p1     = alloc((size_t)E * 9 * 4);       // 92 MB  (layer-1 proj)
  size_t o_p2     = alloc((size_t)E * 20 * 4);      // 205 MB (layer-2 proj)
  bool seq = (off <= ws_size);                      // proj path only if ws fits

  int*   bcnt   = (int*)(base + o_bcnt);
  float* h3     = (float*)(base + o_h3);
  int*   bbase  = (int*)(base + o_bbase);
  int2*  stage  = (int2*)(base + o_stage);
  int*   rowptr = (int*)(base + o_rowptr);
  int*   deg    = (int*)(base + o_deg);
  int*   srcc   = (int*)(base + o_srcc);
  int*   eidc   = (int*)(base + o_eidc);
  float* xl1    = (float*)(base + o_xl1);
  float* xr1    = (float*)(base + o_xr1);
  float* xl2    = (float*)(base + o_xl2);
  float* xr2    = (float*)(base + o_xr2);
  float* h1     = (float*)(base + o_h1);
  float* h2     = (float*)(base + o_h2);
  float* p1     = (float*)(base + o_p1);
  float* p2     = (float*)(base + o_p2);

  hipMemsetAsync(d_ws, 0, zeroBytes, stream);

  // node linears layer 1 (independent)
  k_lin1<<<gridFor((size_t)N * 18), TPB, 0, stream>>>(x, W1l, b1l, W1r, b1r, xl1, xr1, N);

  // binned CSR build
  int binBlocks = (int)(((size_t)E + TPB * ITEMS - 1) / (TPB * ITEMS));
  k_bin<<<binBlocks, TPB, 0, stream>>>(ei, bcnt, stage, E, NB);
  k_scanb<<<1, MAXNB, 0, stream>>>(bcnt, bbase, NB);
  k_csr<<<NB, TPB, 0, stream>>>(stage, bcnt, bbase, rowptr, deg, srcc, eidc, N);

  // gather + project edge attrs for both layers, CSR slot order (one-shot)
  if (seq)
    k_rproj<<<gridFor((size_t)E * 16), TPB, 0, stream>>>(
        eidc, (const float4*)eattr, We1, We2, p1, p2, E);

  // ---- GATv2 layer 1 (H=3, C=3), 4 lanes per (n,h) row ----
  if (seq)
    k_attn<3, 3, 4, true><<<gridFor((size_t)N * 3 * 4), TPB, 0, stream>>>(
        rowptr, deg, srcc, eidc, p1, xl1, xr1, nullptr, att1, nullptr, h1, N);
  else
    k_attn<3, 3, 4, false><<<gridFor((size_t)N * 3 * 4), TPB, 0, stream>>>(
        rowptr, deg, srcc, eidc, eattr, xl1, xr1, We1, att1, nullptr, h1, N);

  // node linears layer 2
  k_lin2<<<gridFor((size_t)N * 40), TPB, 0, stream>>>(h1, bias1, W2l, b2l, W2r, b2r, xl2, xr2, N);

  // ---- GATv2 layer 2 (H=4, C=5), fused bias2+relu, 4 lanes per row ----
  if (seq)
    k_attn<4, 5, 4, true><<<gridFor((size_t)N * 4 * 4), TPB, 0, stream>>>(
        rowptr, deg, srcc, eidc, p2, xl2, xr2, nullptr, att2, bias2, h2, N);
  else
    k_attn<4, 5, 4, false><<<gridFor((size_t)N * 4 * 4), TPB, 0, stream>>>(
        rowptr, deg, srcc, eidc, eattr, xl2, xr2, We2, att2, bias2, h2, N);

  // FC head
  const int NN = num_nodes * 20;   // 100000
  const int KS = 16;
  const int Kc = (NN + KS - 1) / KS;
  dim3 g1(100, KS);
  k_fc1<<<g1, TPB, 0, stream>>>(h2, fcW1, h3, NN, Kc);
  k_fc23<<<1, TPB, 0, stream>>>(h3, fcb1, fcW2, fcb2, fcW3, fcb3, out, B);
  (void)out_size; (void)n_in;
}

// Round 6
// 783.343 us; speedup vs baseline: 1.3404x; 1.3404x over previous
//
#include <hip/hip_runtime.h>
#include <math.h>

#define TPB   256
#define NPB   256      // nodes per bucket (shift 8)
#define MAXNB 512      // supports N <= 131072
#define BCAP  10240    // staging capacity per bucket (expected 8192, sigma~90 -> no overflow)
#define ITEMS 16       // edges per thread in phase-1 tile (625 blocks -> 2.4/CU)
#define CPAD  16       // pad bucket counters to one per 64B line

static inline int gridFor(size_t n) { return (int)((n + TPB - 1) / TPB); }

// ================= node linear transforms =================

__global__ void __launch_bounds__(TPB) k_lin1(
    const float* __restrict__ x,
    const float* __restrict__ Wl, const float* __restrict__ bl,
    const float* __restrict__ Wr, const float* __restrict__ br,
    float* __restrict__ xl, float* __restrict__ xr, int N)
{
  int idx = blockIdx.x * TPB + threadIdx.x;
  if (idx >= N * 18) return;
  int i = idx / 18, t = idx % 18;
  bool left = t < 9;
  int j = left ? t : t - 9;
  const float4* W4 = (const float4*)((left ? Wl : Wr) + j * 64);
  float s = (left ? bl : br)[j];
  const float4* xi4 = (const float4*)(x + (size_t)i * 64);
#pragma unroll
  for (int f = 0; f < 16; f++) {
    float4 xv = xi4[f], wv = W4[f];
    s = fmaf(xv.x, wv.x, s);
    s = fmaf(xv.y, wv.y, s);
    s = fmaf(xv.z, wv.z, s);
    s = fmaf(xv.w, wv.w, s);
  }
  (left ? xl : xr)[(size_t)i * 9 + j] = s;
}

__global__ void __launch_bounds__(TPB) k_lin2(
    const float* __restrict__ h1, const float* __restrict__ bias1,
    const float* __restrict__ Wl, const float* __restrict__ bl,
    const float* __restrict__ Wr, const float* __restrict__ br,
    float* __restrict__ xl, float* __restrict__ xr, int N)
{
  int idx = blockIdx.x * TPB + threadIdx.x;
  if (idx >= N * 40) return;
  int i = idx / 40, t = idx % 40;
  float hr[9];
#pragma unroll
  for (int k = 0; k < 9; k++) hr[k] = fmaxf(h1[(size_t)i * 9 + k] + bias1[k], 0.0f);
  bool left = t < 20;
  int j = left ? t : t - 20;
  const float* W = (left ? Wl : Wr) + j * 9;
  float s = (left ? bl : br)[j];
#pragma unroll
  for (int k = 0; k < 9; k++) s = fmaf(hr[k], W[k], s);
  (left ? xl : xr)[(size_t)i * 20 + j] = s;
}

// ============== phase 1: bin edges by dst-bucket (LDS multisplit) ==========
// record: x = eid | (dst_local << 22), y = src.  (E < 2^22, dst_local < 256)

__global__ void __launch_bounds__(TPB) k_bin(
    const int* __restrict__ ei, int* __restrict__ bucketCntP,
    int2* __restrict__ staging, int E, int NB)
{
  __shared__ int hist[MAXNB];
  __shared__ int base[MAXNB];
  int tid = threadIdx.x;
  size_t tile0 = (size_t)blockIdx.x * (TPB * ITEMS);
  for (int i = tid; i < NB; i += TPB) hist[i] = 0;
  __syncthreads();
  for (int it = 0; it < ITEMS; ++it) {
    size_t e = tile0 + (size_t)it * TPB + tid;
    if (e < (size_t)E) {
      int dst = ei[(size_t)E + e];
      atomicAdd(&hist[dst >> 8], 1);
    }
  }
  __syncthreads();
  for (int i = tid; i < NB; i += TPB) {
    int c = hist[i];
    base[i] = c ? atomicAdd(&bucketCntP[(size_t)i * CPAD], c) : 0;
    hist[i] = 0;
  }
  __syncthreads();
  for (int it = 0; it < ITEMS; ++it) {
    size_t e = tile0 + (size_t)it * TPB + tid;
    if (e < (size_t)E) {
      int src = ei[e];
      int dst = ei[(size_t)E + e];
      int b = dst >> 8;
      int r = atomicAdd(&hist[b], 1);
      staging[(size_t)b * BCAP + base[b] + r] =
          make_int2((int)e | ((dst & 255) << 22), src);
    }
  }
}

// ============== scan bucket counts -> bucket edge bases ==============

__global__ void __launch_bounds__(MAXNB) k_scanb(
    const int* __restrict__ bucketCntP, int* __restrict__ bucketBase, int NB)
{
  __shared__ int s[MAXNB];
  int tid = threadIdx.x;
  int v = (tid < NB) ? bucketCntP[(size_t)tid * CPAD] : 0;
  s[tid] = v;
  __syncthreads();
  for (int off = 1; off < MAXNB; off <<= 1) {
    int u = (tid >= off) ? s[tid - off] : 0;
    __syncthreads();
    s[tid] += u;
    __syncthreads();
  }
  if (tid < NB) bucketBase[tid] = s[tid] - v;   // exclusive
}

// ============== phase 2: per-bucket tight CSR (L2-local writes) ============

__global__ void __launch_bounds__(TPB) k_csr(
    const int2* __restrict__ staging, const int* __restrict__ bucketCntP,
    const int* __restrict__ bucketBase,
    int* __restrict__ rowptr, int* __restrict__ degO,
    int* __restrict__ src_csr, int* __restrict__ eid_csr, int N)
{
  int b = blockIdx.x, tid = threadIdx.x;
  int n0 = b << 8;
  int recCnt = bucketCntP[(size_t)b * CPAD];
  int ebase = bucketBase[b];
  const int2* rec = staging + (size_t)b * BCAP;
  __shared__ int deg_s[NPB];
  __shared__ int pfx[NPB];
  __shared__ int cur[NPB];
  deg_s[tid] = 0;
  __syncthreads();
  for (int r = tid; r < recCnt; r += TPB)
    atomicAdd(&deg_s[(rec[r].x >> 22) & 255], 1);
  __syncthreads();
  pfx[tid] = deg_s[tid];
  __syncthreads();
  for (int off = 1; off < NPB; off <<= 1) {
    int u = (tid >= off) ? pfx[tid - off] : 0;
    __syncthreads();
    pfx[tid] += u;
    __syncthreads();
  }
  int excl = pfx[tid] - deg_s[tid];
  int n = n0 + tid;
  if (n < N) { rowptr[n] = ebase + excl; degO[n] = deg_s[tid]; }
  cur[tid] = ebase + excl;
  __syncthreads();
  for (int r = tid; r < recCnt; r += TPB) {
    int2 rc = rec[r];
    int dl = (rc.x >> 22) & 255;
    int eid = rc.x & 0x3FFFFF;
    int pos = atomicAdd(&cur[dl], 1);
    src_csr[pos] = rc.y;
    eid_csr[pos] = eid;
  }
}

// ============== gather-reorder eattr into CSR order ==============
// lane-cooperative: 4 lanes per edge, each moves one float4 -> the 4 lanes'
// 16B reads of the same 64B line coalesce into one transaction, and the
// stores are dense float4 streams.  (Proven shape: fast in rounds 2/3.)

__global__ void __launch_bounds__(TPB) k_reorder(
    const int* __restrict__ eid_csr, const float4* __restrict__ eattr4,
    float4* __restrict__ eac, int E)
{
  int idx = blockIdx.x * TPB + threadIdx.x;
  int slot = idx >> 2;
  int part = idx & 3;
  if (slot >= E) return;
  int eid = eid_csr[slot];                  // broadcast across the 4 lanes
  eac[(size_t)slot * 4 + part] = eattr4[(size_t)eid * 4 + part];
}

// ========== fused GATv2 attention: online softmax, virtual self-loop =======
// L lanes cooperate on one (node, head) row; each lane keeps a partial
// online-softmax state over edges p = lane, lane+L, ...; states merged via
// a shfl_xor butterfly at the end.  SEQ: eattr already CSR-ordered (eac) ->
// 4 lanes of a group read 4 consecutive 64B rows (256B contiguous/iter).

template <int H, int C, int L, bool SEQ>
__global__ void __launch_bounds__(TPB) k_attn(
    const int* __restrict__ rowptr, const int* __restrict__ deg,
    const int* __restrict__ src_csr, const int* __restrict__ eid_csr,
    const float* __restrict__ ea_src,   // eac if SEQ, else original eattr
    const float* __restrict__ xl, const float* __restrict__ xr,
    const float* __restrict__ We, const float* __restrict__ att,
    const float* __restrict__ bias,  // nullptr -> raw output
    float* __restrict__ out, int N)
{
  constexpr int HC = H * C;
  int idx = blockIdx.x * TPB + threadIdx.x;
  if (idx >= N * H * L) return;
  int l = idx & (L - 1);          // lane within group (L divides 64)
  int g = idx / L;                // (node, head) group
  int n = g / H, h = g - n * H;

  float w[C][16];
#pragma unroll
  for (int c = 0; c < C; c++)
#pragma unroll
    for (int f = 0; f < 16; f++) w[c][f] = We[(h * C + c) * 16 + f];
  float attv[C], xrv[C];
#pragma unroll
  for (int c = 0; c < C; c++) {
    attv[c] = att[h * C + c];
    xrv[c] = xr[(size_t)n * HC + h * C + c];
  }

  int r0 = rowptr[n];
  int dg = deg[n];

  // finite sentinel (not -inf) so empty-lane merges give exp(0)=1 on a zero
  // accumulator instead of exp(-inf+inf)=NaN.
  float mx = -3.0e38f, den = 0.0f;
  float acc[C], ea_sum[C];
#pragma unroll
  for (int c = 0; c < C; c++) { acc[c] = 0.0f; ea_sum[c] = 0.0f; }

  for (int p = l; p < dg; p += L) {
    int pos = r0 + p;
    size_t abase = SEQ ? (size_t)pos * 16 : (size_t)eid_csr[pos] * 16;
    float a[16];
    const float4* a4 = (const float4*)(ea_src + abase);
#pragma unroll
    for (int k = 0; k < 4; k++) {
      float4 v = a4[k];
      a[4 * k + 0] = v.x; a[4 * k + 1] = v.y; a[4 * k + 2] = v.z; a[4 * k + 3] = v.w;
    }
    int srcn = src_csr[pos];
    const float* xs = xl + (size_t)srcn * HC + h * C;
    float xv[C];
#pragma unroll
    for (int c = 0; c < C; c++) xv[c] = xs[c];
    float lg = 0.0f;
#pragma unroll
    for (int c = 0; c < C; c++) {
      float ea = 0.0f;
#pragma unroll
      for (int f = 0; f < 16; f++) ea = fmaf(a[f], w[c][f], ea);
      ea_sum[c] += ea;
      float m = xv[c] + xrv[c] + ea;
      m = (m >= 0.0f) ? m : 0.2f * m;
      lg = fmaf(m, attv[c], lg);
    }
    float nm = fmaxf(mx, lg);
    float s = expf(mx - nm);     // 0 when mx is sentinel and lg real
    float wE = expf(lg - nm);
    den = den * s + wE;
#pragma unroll
    for (int c = 0; c < C; c++) acc[c] = fmaf(acc[c], s, wE * xv[c]);
    mx = nm;
  }

  // ---- merge the L partial online-softmax states (xor butterfly) ----
#pragma unroll
  for (int off = 1; off < L; off <<= 1) {
    float omx  = __shfl_xor(mx, off, 64);
    float oden = __shfl_xor(den, off, 64);
    float nm = fmaxf(mx, omx);
    float s1 = expf(mx - nm);    // both sentinel -> exp(0)=1, scales zeros
    float s2 = expf(omx - nm);
    den = den * s1 + oden * s2;
#pragma unroll
    for (int c = 0; c < C; c++) {
      float oa = __shfl_xor(acc[c], off, 64);
      float oe = __shfl_xor(ea_sum[c], off, 64);
      acc[c] = acc[c] * s1 + oa * s2;
      ea_sum[c] += oe;
    }
    mx = nm;
  }

  // virtual self-loop: src = n, attr projection = mean of edge projections
  // (computed redundantly on all L lanes -- identical merged state)
  {
    float invd = 1.0f / fmaxf((float)dg, 1.0f);
    const float* xs = xl + (size_t)n * HC + h * C;
    float xv[C];
#pragma unroll
    for (int c = 0; c < C; c++) xv[c] = xs[c];
    float lg = 0.0f;
#pragma unroll
    for (int c = 0; c < C; c++) {
      float m = xv[c] + xrv[c] + ea_sum[c] * invd;
      m = (m >= 0.0f) ? m : 0.2f * m;
      lg = fmaf(m, attv[c], lg);
    }
    float nm = fmaxf(mx, lg);
    float s = expf(mx - nm);
    float wE = expf(lg - nm);
    den = den * s + wE;
#pragma unroll
    for (int c = 0; c < C; c++) acc[c] = fmaf(acc[c], s, wE * xv[c]);
  }

  float inv = 1.0f / den;
  float* od = out + (size_t)n * HC + h * C;
  // lane-partitioned channel writes
  for (int c = l; c < C; c += L) {
    float v = acc[c] * inv;
    if (bias) v = fmaxf(v + bias[h * C + c], 0.0f);
    od[c] = v;
  }
}

// ================= FC head =================

__global__ void __launch_bounds__(TPB) k_fc1(
    const float* __restrict__ h2, const float* __restrict__ W,
    float* __restrict__ h3, int NN, int Kc)
{
  int o = blockIdx.x;
  int ks = blockIdx.y;
  int k0 = ks * Kc;
  int k1 = min(NN, k0 + Kc);
  float acc[16];
#pragma unroll
  for (int b = 0; b < 16; b++) acc[b] = 0.0f;
  const float* wo = W + (size_t)o * NN;
  for (int k = k0 + threadIdx.x; k < k1; k += TPB) {
    float w = wo[k];
#pragma unroll
    for (int b = 0; b < 16; b++) acc[b] = fmaf(h2[(size_t)b * NN + k], w, acc[b]);
  }
#pragma unroll
  for (int b = 0; b < 16; b++) {
    float v = acc[b];
#pragma unroll
    for (int off = 32; off > 0; off >>= 1) v += __shfl_down(v, off, 64);
    if ((threadIdx.x & 63) == 0) atomicAdd(&h3[b * 100 + o], v);
  }
}

__global__ void __launch_bounds__(TPB) k_fc23(
    const float* __restrict__ h3, const float* __restrict__ fcb1,
    const float* __restrict__ W2, const float* __restrict__ b2,
    const float* __restrict__ W3, const float* __restrict__ b3,
    float* __restrict__ out, int B)
{
  __shared__ float s3[32 * 100];
  __shared__ float s4[32 * 10];
  int tid = threadIdx.x;
  for (int t = tid; t < B * 100; t += TPB)
    s3[t] = fmaxf(h3[t] + fcb1[t % 100], 0.0f);
  __syncthreads();
  if (tid < B * 10) {
    int b = tid / 10, o = tid % 10;
    float s = b2[o];
#pragma unroll
    for (int k = 0; k < 100; k++) s = fmaf(s3[b * 100 + k], W2[o * 100 + k], s);
    s4[tid] = fmaxf(s, 0.0f);
  }
  __syncthreads();
  if (tid < B) {
    float s = b3[0];
#pragma unroll
    for (int k = 0; k < 10; k++) s = fmaf(s4[tid * 10 + k], W3[k], s);
    out[tid] = s;
  }
}

// ================= launch =================

extern "C" void kernel_launch(void* const* d_in, const int* in_sizes, int n_in,
                              void* d_out, int out_size, void* d_ws, size_t ws_size,
                              hipStream_t stream) {
  const float* x      = (const float*)d_in[0];
  const int*   ei     = (const int*)d_in[1];
  const float* eattr  = (const float*)d_in[2];
  const float* W1l = (const float*)d_in[4];  const float* b1l = (const float*)d_in[5];
  const float* W1r = (const float*)d_in[6];  const float* b1r = (const float*)d_in[7];
  const float* We1 = (const float*)d_in[8];  const float* att1 = (const float*)d_in[9];
  const float* bias1 = (const float*)d_in[10];
  const float* W2l = (const float*)d_in[11]; const float* b2l = (const float*)d_in[12];
  const float* W2r = (const float*)d_in[13]; const float* b2r = (const float*)d_in[14];
  const float* We2 = (const float*)d_in[15]; const float* att2 = (const float*)d_in[16];
  const float* bias2 = (const float*)d_in[17];
  const float* fcW1 = (const float*)d_in[18]; const float* fcb1 = (const float*)d_in[19];
  const float* fcW2 = (const float*)d_in[20]; const float* fcb2 = (const float*)d_in[21];
  const float* fcW3 = (const float*)d_in[22]; const float* fcb3 = (const float*)d_in[23];
  float* out = (float*)d_out;

  const int N = in_sizes[0] / 64;                   // 80000
  const int E = in_sizes[2] / 16;                   // 2560000
  const int num_nodes = in_sizes[18] / (100 * 20);  // 5000
  const int B = N / num_nodes;                      // 16
  const int NB = (N + NPB - 1) / NPB;               // 313

  // ---- workspace layout (64B aligned chunks) ----
  char* base = (char*)d_ws;
  size_t off = 0;
  auto alloc = [&](size_t bytes) {
    size_t o = off; off += (bytes + 63) & ~(size_t)63; return o;
  };
  // zero-init region: padded bucket counters + h3
  size_t o_bcnt   = alloc((size_t)NB * CPAD * 4);
  size_t o_h3     = alloc((size_t)B * 100 * 4);
  size_t zeroBytes = off;
  size_t o_bbase  = alloc((size_t)NB * 4);
  size_t o_stage  = alloc((size_t)NB * BCAP * 8);
  size_t o_rowptr = alloc((size_t)N * 4);
  size_t o_deg    = alloc((size_t)N * 4);
  size_t o_srcc   = alloc((size_t)E * 4);
  size_t o_eidc   = alloc((size_t)E * 4);
  size_t o_xl1    = alloc((size_t)N * 9 * 4);
  size_t o_xr1    = alloc((size_t)N * 9 * 4);
  size_t o_xl2    = alloc((size_t)N * 20 * 4);
  size_t o_xr2    = alloc((size_t)N * 20 * 4);
  size_t o_h1     = alloc((size_t)N * 9 * 4);
  size_t o_h2     = alloc((size_t)N * 20 * 4);
  size_t o_eac    = alloc((size_t)E * 16 * 4);      // 164 MB, optional
  bool seq = (off <= ws_size);                      // reorder only if ws fits

  int*   bcnt   = (int*)(base + o_bcnt);
  float* h3     = (float*)(base + o_h3);
  int*   bbase  = (int*)(base + o_bbase);
  int2*  stage  = (int2*)(base + o_stage);
  int*   rowptr = (int*)(base + o_rowptr);
  int*   deg    = (int*)(base + o_deg);
  int*   srcc   = (int*)(base + o_srcc);
  int*   eidc   = (int*)(base + o_eidc);
  float* xl1    = (float*)(base + o_xl1);
  float* xr1    = (float*)(base + o_xr1);
  float* xl2    = (float*)(base + o_xl2);
  float* xr2    = (float*)(base + o_xr2);
  float* h1     = (float*)(base + o_h1);
  float* h2     = (float*)(base + o_h2);
  float* eac    = (float*)(base + o_eac);

  hipMemsetAsync(d_ws, 0, zeroBytes, stream);

  // node linears layer 1 (independent)
  k_lin1<<<gridFor((size_t)N * 18), TPB, 0, stream>>>(x, W1l, b1l, W1r, b1r, xl1, xr1, N);

  // binned CSR build
  int binBlocks = (int)(((size_t)E + TPB * ITEMS - 1) / (TPB * ITEMS));
  k_bin<<<binBlocks, TPB, 0, stream>>>(ei, bcnt, stage, E, NB);
  k_scanb<<<1, MAXNB, 0, stream>>>(bcnt, bbase, NB);
  k_csr<<<NB, TPB, 0, stream>>>(stage, bcnt, bbase, rowptr, deg, srcc, eidc, N);
  if (seq)
    k_reorder<<<gridFor((size_t)E * 4), TPB, 0, stream>>>(
        eidc, (const float4*)eattr, (float4*)eac, E);

  // ---- GATv2 layer 1 (H=3, C=3), 4 lanes per (n,h) row ----
  if (seq)
    k_attn<3, 3, 4, true><<<gridFor((size_t)N * 3 * 4), TPB, 0, stream>>>(
        rowptr, deg, srcc, eidc, eac, xl1, xr1, We1, att1, nullptr, h1, N);
  else
    k_attn<3, 3, 4, false><<<gridFor((size_t)N * 3 * 4), TPB, 0, stream>>>(
        rowptr, deg, srcc, eidc, eattr, xl1, xr1, We1, att1, nullptr, h1, N);

  // node linears layer 2
  k_lin2<<<gridFor((size_t)N * 40), TPB, 0, stream>>>(h1, bias1, W2l, b2l, W2r, b2r, xl2, xr2, N);

  // ---- GATv2 layer 2 (H=4, C=5), fused bias2+relu, 4 lanes per row ----
  if (seq)
    k_attn<4, 5, 4, true><<<gridFor((size_t)N * 4 * 4), TPB, 0, stream>>>(
        rowptr, deg, srcc, eidc, eac, xl2, xr2, We2, att2, bias2, h2, N);
  else
    k_attn<4, 5, 4, false><<<gridFor((size_t)N * 4 * 4), TPB, 0, stream>>>(
        rowptr, deg, srcc, eidc, eattr, xl2, xr2, We2, att2, bias2, h2, N);

  // FC head
  const int NN = num_nodes * 20;   // 100000
  const int KS = 16;
  const int Kc = (NN + KS - 1) / KS;
  dim3 g1(100, KS);
  k_fc1<<<g1, TPB, 0, stream>>>(h2, fcW1, h3, NN, Kc);
  k_fc23<<<1, TPB, 0, stream>>>(h3, fcb1, fcW2, fcb2, fcW3, fcb3, out, B);
  (void)out_size; (void)n_in;
}